// Round 1
// baseline (8200.603 us; speedup 1.0000x reference)
//
#include <hip/hip_runtime.h>

// Problem constants
#define T36   36
#define NPAR  161
#define PP    176          // NP padded to 16*11
#define MM    50
#define NN    4096
#define NCOLS (NN*MM)      // 204800
#define COLS_PER_BLK 64
#define DWS   (T36*PP)     // 6336 floats of D in workspace, then [Linv, wl]

// ---------------------------------------------------------------------------
// Setup: build normalized dictionary D [36][176] (zero-padded cols >=161),
// compute L = ||DtD||_2 via the 36x36 Gram matrix E = D D^T (same spectrum),
// using scaled repeated squaring (projector extraction) + Rayleigh quotient.
// Writes: ws[0..6335] = D, ws[6336] = 1/L, ws[6337] = 0.005/L.
// ---------------------------------------------------------------------------
__global__ __launch_bounds__(256) void setup_kernel(const float* __restrict__ r,
                                                    const float* __restrict__ th,
                                                    float* __restrict__ ws) {
  __shared__ float Dl[T36][PP];
  __shared__ float El[T36][T36];
  __shared__ float Fl[T36][T36];
  __shared__ float Gl[T36][T36];
  __shared__ float vl[T36], v2[T36], v3[T36];
  __shared__ float sc;
  __shared__ int jmaxs;
  const int tid = threadIdx.x;

  for (int e = tid; e < T36*PP; e += 256) (&Dl[0][0])[e] = 0.0f;
  __syncthreads();

  if (tid < NPAR) {
    const int p = tid;
    float col[T36];
    if (p == 0) {
      #pragma unroll
      for (int t = 0; t < T36; ++t) col[t] = 1.0f;  // 1+1e-10 rounds to 1.0f
    } else if (p <= 80) {
      const float a = r[p-1], w = th[p-1];
      for (int t = 0; t < T36; ++t) col[t] = powf(a, (float)t) * cosf((float)t * w);
    } else {
      const float a = r[p-81], w = th[p-81];
      for (int t = 0; t < T36; ++t) col[t] = powf(a, (float)t) * sinf((float)t * w);
    }
    float s = 0.0f;
    for (int t = 0; t < T36; ++t) s += col[t]*col[t];
    const float inv = 1.0f / sqrtf(s);
    for (int t = 0; t < T36; ++t) Dl[t][p] = col[t] * inv;
  }
  __syncthreads();

  for (int e = tid; e < T36*PP; e += 256) ws[e] = (&Dl[0][0])[e];

  // E = D D^T  (36x36, PSD; nonzero spectrum == spectrum of DtD)
  for (int e = tid; e < T36*T36; e += 256) {
    const int a = e / T36, b = e % T36;
    float s = 0.0f;
    for (int p = 0; p < PP; ++p) s += Dl[a][p]*Dl[b][p];
    El[a][b] = s; Fl[a][b] = s;
  }

  // 25 scaled squarings: F <- (F*F)/trace(F*F)  -> rank-1 projector u u^T
  for (int it = 0; it < 25; ++it) {
    __syncthreads();
    for (int e = tid; e < T36*T36; e += 256) {
      const int a = e / T36, b = e % T36;
      float s = 0.0f;
      for (int k = 0; k < T36; ++k) s += Fl[a][k]*Fl[k][b];
      Gl[a][b] = s;
    }
    __syncthreads();
    if (tid == 0) {
      float tr = 0.0f;
      for (int i = 0; i < T36; ++i) tr += Gl[i][i];
      sc = 1.0f / tr;
    }
    __syncthreads();
    for (int e = tid; e < T36*T36; e += 256) {
      const int a = e / T36, b = e % T36;
      Fl[a][b] = Gl[a][b] * sc;
    }
  }
  __syncthreads();

  if (tid == 0) {
    int jm = 0; float bm = Fl[0][0];
    for (int i = 1; i < T36; ++i) if (Fl[i][i] > bm) { bm = Fl[i][i]; jm = i; }
    jmaxs = jm;
  }
  __syncthreads();
  if (tid < T36) vl[tid] = Fl[tid][jmaxs];
  __syncthreads();
  if (tid < T36) { float s = 0.0f; for (int k = 0; k < T36; ++k) s += El[tid][k]*vl[k]; v2[tid] = s; }
  __syncthreads();
  if (tid < T36) { float s = 0.0f; for (int k = 0; k < T36; ++k) s += El[tid][k]*v2[k]; v3[tid] = s; }
  __syncthreads();
  if (tid == 0) {
    float num = 0.0f, den = 0.0f;
    for (int t = 0; t < T36; ++t) { num += v3[t]*v2[t]; den += v2[t]*v2[t]; }
    const float L = num / den;     // Rayleigh quotient on E with polished vector
    ws[DWS]   = 1.0f / L;          // Linv
    ws[DWS+1] = 0.005f / L;        // lambda * Linv  (w == 1)
  }
}

// ---------------------------------------------------------------------------
// Main FISTA kernel. One block = 64 columns (n,m pairs). State:
//   Yl (y-state) [176][64] in LDS; x_old + const (DtY*Linv) in registers.
// Per iteration (factored A):  V = D*Y (36x64);  u = D^T*V;  elementwise
// soft-threshold + momentum, y-state rewritten in LDS.
// Thread roles: pg=tid>>4 (16), ct=tid&15 (16). Elementwise/phase-2 ownership:
//   p = pg+16j (j=0..10), c = 4ct..4ct+3. Phase 1: rows t=3*pg..3*pg+2 (pg<12).
// ---------------------------------------------------------------------------
__global__ __launch_bounds__(256, 2) void fista_kernel(const float* __restrict__ y,
                                                       const float* __restrict__ ws,
                                                       float* __restrict__ out) {
  __shared__ float Dl[T36][PP];     // 25344 B
  __shared__ float Yl[PP][COLS_PER_BLK];   // 45056 B
  __shared__ float Vl[T36][COLS_PER_BLK];  //  9216 B
  const int tid = threadIdx.x;
  const int g0 = blockIdx.x * COLS_PER_BLK;

  for (int e = tid; e < T36*PP; e += 256) (&Dl[0][0])[e] = ws[e];
  const float Linv = ws[DWS];
  const float wl   = ws[DWS+1];
  for (int e = tid; e < PP*COLS_PER_BLK; e += 256) (&Yl[0][0])[e] = 0.0f;
  // stage Y0 tile (36 x 64) into Vl
  for (int e = tid; e < T36*COLS_PER_BLK; e += 256) {
    const int t = e >> 6, c = e & 63;
    const int gc = g0 + c;
    const int n = gc / 50, m = gc - n*50;
    Vl[t][c] = y[(size_t)n*1800 + t*50 + m];
  }
  __syncthreads();

  const int pg = tid >> 4;
  const int ct = tid & 15;
  const int c0 = ct * 4;

  float cv[11][4];   // DtY * Linv  (const)
  float xo[11][4];   // x_old

  {  // cv = Linv * D^T * Y0   (Y0 currently in Vl)
    float acc[11][4];
    #pragma unroll
    for (int j = 0; j < 11; ++j)
      #pragma unroll
      for (int cc = 0; cc < 4; ++cc) acc[j][cc] = 0.0f;
    for (int t = 0; t < T36; ++t) {
      const float4 v = *reinterpret_cast<const float4*>(&Vl[t][c0]);
      float d[11];
      #pragma unroll
      for (int j = 0; j < 11; ++j) d[j] = Dl[t][pg + 16*j];
      #pragma unroll
      for (int j = 0; j < 11; ++j) {
        acc[j][0] = fmaf(d[j], v.x, acc[j][0]);
        acc[j][1] = fmaf(d[j], v.y, acc[j][1]);
        acc[j][2] = fmaf(d[j], v.z, acc[j][2]);
        acc[j][3] = fmaf(d[j], v.w, acc[j][3]);
      }
    }
    #pragma unroll
    for (int j = 0; j < 11; ++j)
      #pragma unroll
      for (int cc = 0; cc < 4; ++cc) { cv[j][cc] = acc[j][cc] * Linv; xo[j][cc] = 0.0f; }
  }

  float tk = 1.0f;
  for (int it = 0; it < 100; ++it) {
    __syncthreads();   // y-state (Yl) ready; Vl free to overwrite
    // Phase 1: V[t][c] = sum_p D[t][p] * Y[p][c];  rows t=3*pg..3*pg+2
    if (pg < 12) {
      const int t0 = 3*pg;
      float a0[4], a1[4], a2[4];
      #pragma unroll
      for (int cc = 0; cc < 4; ++cc) { a0[cc] = 0.0f; a1[cc] = 0.0f; a2[cc] = 0.0f; }
      for (int k = 0; k < PP; ++k) {
        const float4 yv = *reinterpret_cast<const float4*>(&Yl[k][c0]);
        const float d0 = Dl[t0+0][k];
        const float d1 = Dl[t0+1][k];
        const float d2 = Dl[t0+2][k];
        a0[0]=fmaf(d0,yv.x,a0[0]); a0[1]=fmaf(d0,yv.y,a0[1]); a0[2]=fmaf(d0,yv.z,a0[2]); a0[3]=fmaf(d0,yv.w,a0[3]);
        a1[0]=fmaf(d1,yv.x,a1[0]); a1[1]=fmaf(d1,yv.y,a1[1]); a1[2]=fmaf(d1,yv.z,a1[2]); a1[3]=fmaf(d1,yv.w,a1[3]);
        a2[0]=fmaf(d2,yv.x,a2[0]); a2[1]=fmaf(d2,yv.y,a2[1]); a2[2]=fmaf(d2,yv.z,a2[2]); a2[3]=fmaf(d2,yv.w,a2[3]);
      }
      *reinterpret_cast<float4*>(&Vl[t0+0][c0]) = make_float4(a0[0],a0[1],a0[2],a0[3]);
      *reinterpret_cast<float4*>(&Vl[t0+1][c0]) = make_float4(a1[0],a1[1],a1[2],a1[3]);
      *reinterpret_cast<float4*>(&Vl[t0+2][c0]) = make_float4(a2[0],a2[1],a2[2],a2[3]);
    }
    __syncthreads();

    const float tnew = 0.5f*(1.0f + sqrtf(fmaf(4.0f*tk, tk, 1.0f)));
    const float tt   = (tk - 1.0f) / tnew;
    tk = tnew;

    // Phase 2: u[p][c] = sum_t D[t][p] * V[t][c];  then elementwise update
    float u[11][4];
    #pragma unroll
    for (int j = 0; j < 11; ++j)
      #pragma unroll
      for (int cc = 0; cc < 4; ++cc) u[j][cc] = 0.0f;
    for (int t = 0; t < T36; ++t) {
      const float4 v = *reinterpret_cast<const float4*>(&Vl[t][c0]);
      float d[11];
      #pragma unroll
      for (int j = 0; j < 11; ++j) d[j] = Dl[t][pg + 16*j];
      #pragma unroll
      for (int j = 0; j < 11; ++j) {
        u[j][0] = fmaf(d[j], v.x, u[j][0]);
        u[j][1] = fmaf(d[j], v.y, u[j][1]);
        u[j][2] = fmaf(d[j], v.z, u[j][2]);
        u[j][3] = fmaf(d[j], v.w, u[j][3]);
      }
    }
    #pragma unroll
    for (int j = 0; j < 11; ++j) {
      const int p = pg + 16*j;
      const float4 yv = *reinterpret_cast<const float4*>(&Yl[p][c0]);
      float yy[4] = {yv.x, yv.y, yv.z, yv.w};
      float yn[4];
      #pragma unroll
      for (int cc = 0; cc < 4; ++cc) {
        const float gq = fmaf(-Linv, u[j][cc], yy[cc]) + cv[j][cc];   // Ay + DtY*Linv
        const float xn = fmaxf(0.0f, gq - wl) + fminf(0.0f, gq + wl); // soft-threshold
        yn[cc] = fmaf(tt, xn - xo[j][cc], xn);
        xo[j][cc] = xn;
      }
      *reinterpret_cast<float4*>(&Yl[p][c0]) = make_float4(yn[0],yn[1],yn[2],yn[3]);
    }
  }

  // Epilogue: Yl <- x_final (own slots only; no reader until barrier)
  #pragma unroll
  for (int j = 0; j < 11; ++j)
    *reinterpret_cast<float4*>(&Yl[pg + 16*j][c0]) = make_float4(xo[j][0],xo[j][1],xo[j][2],xo[j][3]);
  __syncthreads();

  const size_t YP = (size_t)NN * T36 * MM;   // 7,372,800 floats of Y_pred
  // Y_pred tile = D * x_final (same shape as phase 1), written straight out
  if (pg < 12) {
    const int t0 = 3*pg;
    float a0[4], a1[4], a2[4];
    #pragma unroll
    for (int cc = 0; cc < 4; ++cc) { a0[cc] = 0.0f; a1[cc] = 0.0f; a2[cc] = 0.0f; }
    for (int k = 0; k < PP; ++k) {
      const float4 yv = *reinterpret_cast<const float4*>(&Yl[k][c0]);
      const float d0 = Dl[t0+0][k];
      const float d1 = Dl[t0+1][k];
      const float d2 = Dl[t0+2][k];
      a0[0]=fmaf(d0,yv.x,a0[0]); a0[1]=fmaf(d0,yv.y,a0[1]); a0[2]=fmaf(d0,yv.z,a0[2]); a0[3]=fmaf(d0,yv.w,a0[3]);
      a1[0]=fmaf(d1,yv.x,a1[0]); a1[1]=fmaf(d1,yv.y,a1[1]); a1[2]=fmaf(d1,yv.z,a1[2]); a1[3]=fmaf(d1,yv.w,a1[3]);
      a2[0]=fmaf(d2,yv.x,a2[0]); a2[1]=fmaf(d2,yv.y,a2[1]); a2[2]=fmaf(d2,yv.z,a2[2]); a2[3]=fmaf(d2,yv.w,a2[3]);
    }
    #pragma unroll
    for (int cc = 0; cc < 4; ++cc) {
      const int gc = g0 + c0 + cc;
      const int n = gc / 50, m = gc - n*50;
      out[(size_t)n*1800 + (t0+0)*50 + m] = a0[cc];
      out[(size_t)n*1800 + (t0+1)*50 + m] = a1[cc];
      out[(size_t)n*1800 + (t0+2)*50 + m] = a2[cc];
    }
  }
  // C_pred = x_final
  #pragma unroll
  for (int j = 0; j < 11; ++j) {
    const int p = pg + 16*j;
    if (p < NPAR) {
      #pragma unroll
      for (int cc = 0; cc < 4; ++cc) {
        const int gc = g0 + c0 + cc;
        const int n = gc / 50, m = gc - n*50;
        out[YP + (size_t)n*(NPAR*MM) + (size_t)p*MM + m] = xo[j][cc];
      }
    }
  }
}

extern "C" void kernel_launch(void* const* d_in, const int* in_sizes, int n_in,
                              void* d_out, int out_size, void* d_ws, size_t ws_size,
                              hipStream_t stream) {
  const float* y  = (const float*)d_in[0];
  const float* r  = (const float*)d_in[1];
  const float* th = (const float*)d_in[2];
  float* out = (float*)d_out;
  float* ws  = (float*)d_ws;

  setup_kernel<<<1, 256, 0, stream>>>(r, th, ws);
  fista_kernel<<<NCOLS / COLS_PER_BLK, 256, 0, stream>>>(y, ws, out);
}

// Round 2
// 3030.505 us; speedup vs baseline: 2.7060x; 2.7060x over previous
//
#include <hip/hip_runtime.h>

// Problem constants
#define T36   36
#define NPAR  161
#define MM    50
#define NN    4096
#define NCOLS (NN*MM)      // 204800
// Padded dims for MFMA
#define MP    48           // D rows padded 36 -> 48 (3 row-tiles of 16)
#define KP    192          // NP padded 161 -> 192 (6 k-steps of 32)
#define KV    64           // V k-dim padded 48 -> 64 (2 k-steps of 32)
#define CB    32           // columns per block
#define YPITCH 200         // f16 pitch for Y-state rows (192+8): bank-uniform
#define VPITCH 72          // f16 pitch for V rows (64+8)

typedef _Float16 half8 __attribute__((ext_vector_type(8)));
typedef _Float16 half4 __attribute__((ext_vector_type(4)));
typedef float    f32x4 __attribute__((ext_vector_type(4)));

#define MFMA16(a,b,c) __builtin_amdgcn_mfma_f32_16x16x32_f16(a,b,c,0,0,0)

// D (fp32, [48][192] row-major) ; DT (fp32, [192][64]) ; [Linv, lambda*Linv]
__device__ float g_D[MP*KP];
__device__ float g_DT[KP*KV];
__device__ float g_sc[2];

// ---------------------------------------------------------------------------
// Setup: build normalized dictionary into g_D/g_DT, compute L = ||DtD||_2 via
// the 36x36 Gram matrix E = D D^T (same nonzero spectrum), scaled repeated
// squaring -> dominant eigvec -> Rayleigh quotient. (Validated in round 1.)
// ---------------------------------------------------------------------------
__global__ __launch_bounds__(256) void setup_kernel(const float* __restrict__ r,
                                                    const float* __restrict__ th) {
  __shared__ float Dl[MP][KP];      // 36.9 KB
  __shared__ float El[T36][T36];
  __shared__ float Fl[T36][T36];
  __shared__ float Gl[T36][T36];
  __shared__ float vl[T36], v2[T36], v3[T36];
  __shared__ float sc;
  __shared__ int jmaxs;
  const int tid = threadIdx.x;

  for (int e = tid; e < MP*KP; e += 256) (&Dl[0][0])[e] = 0.0f;
  __syncthreads();

  if (tid < NPAR) {
    const int p = tid;
    float col[T36];
    if (p == 0) {
      #pragma unroll
      for (int t = 0; t < T36; ++t) col[t] = 1.0f;   // 1+1e-10 rounds to 1.0f
    } else if (p <= 80) {
      const float a = r[p-1], w = th[p-1];
      for (int t = 0; t < T36; ++t) col[t] = powf(a, (float)t) * cosf((float)t * w);
    } else {
      const float a = r[p-81], w = th[p-81];
      for (int t = 0; t < T36; ++t) col[t] = powf(a, (float)t) * sinf((float)t * w);
    }
    float s = 0.0f;
    for (int t = 0; t < T36; ++t) s += col[t]*col[t];
    const float inv = 1.0f / sqrtf(s);
    for (int t = 0; t < T36; ++t) Dl[t][p] = col[t] * inv;
  }
  __syncthreads();

  // publish D and DT (fp32)
  for (int e = tid; e < MP*KP; e += 256) g_D[e] = (&Dl[0][0])[e];
  for (int e = tid; e < KP*KV; e += 256) {
    const int p = e / KV, t = e % KV;
    g_DT[e] = (t < MP) ? Dl[t][p] : 0.0f;
  }

  // E = D D^T (36x36)
  for (int e = tid; e < T36*T36; e += 256) {
    const int a = e / T36, b = e % T36;
    float s = 0.0f;
    for (int p = 0; p < KP; ++p) s += Dl[a][p]*Dl[b][p];
    El[a][b] = s; Fl[a][b] = s;
  }

  for (int it = 0; it < 25; ++it) {
    __syncthreads();
    for (int e = tid; e < T36*T36; e += 256) {
      const int a = e / T36, b = e % T36;
      float s = 0.0f;
      for (int k = 0; k < T36; ++k) s += Fl[a][k]*Fl[k][b];
      Gl[a][b] = s;
    }
    __syncthreads();
    if (tid == 0) {
      float tr = 0.0f;
      for (int i = 0; i < T36; ++i) tr += Gl[i][i];
      sc = 1.0f / tr;
    }
    __syncthreads();
    for (int e = tid; e < T36*T36; e += 256) {
      const int a = e / T36, b = e % T36;
      Fl[a][b] = Gl[a][b] * sc;
    }
  }
  __syncthreads();

  if (tid == 0) {
    int jm = 0; float bm = Fl[0][0];
    for (int i = 1; i < T36; ++i) if (Fl[i][i] > bm) { bm = Fl[i][i]; jm = i; }
    jmaxs = jm;
  }
  __syncthreads();
  if (tid < T36) vl[tid] = Fl[tid][jmaxs];
  __syncthreads();
  if (tid < T36) { float s = 0.0f; for (int k = 0; k < T36; ++k) s += El[tid][k]*vl[k]; v2[tid] = s; }
  __syncthreads();
  if (tid < T36) { float s = 0.0f; for (int k = 0; k < T36; ++k) s += El[tid][k]*v2[k]; v3[tid] = s; }
  __syncthreads();
  if (tid == 0) {
    float num = 0.0f, den = 0.0f;
    for (int t = 0; t < T36; ++t) { num += v3[t]*v2[t]; den += v2[t]*v2[t]; }
    const float L = num / den;
    g_sc[0] = 1.0f / L;
    g_sc[1] = 0.005f / L;
  }
}

// ---------------------------------------------------------------------------
// FISTA via f16 split-2/3-product MFMA. Block = 32 cols, 4 waves.
//   GEMM1: V[48][32]  = D[48][192] x Y[192][32]   (waves 0-2, row-tile = wave)
//   GEMM2: U[192][32] = DT[192][64] x V[64][32]   (all waves, 3 p-tiles each)
// D/DT fragments live in REGISTERS (constant across 100 iters); Y-state and V
// transit LDS as separate f16 hi/lo arrays (b128-readable, bank-uniform).
// y fp32 / x_old / cv stay in registers in the GEMM2-output distribution.
// ---------------------------------------------------------------------------
__global__ __launch_bounds__(256, 2) void fista_kernel(const float* __restrict__ y,
                                                       float* __restrict__ out) {
  __shared__ __align__(16) _Float16 Yh[CB][YPITCH];   // 12.5 KB
  __shared__ __align__(16) _Float16 Yl[CB][YPITCH];   // 12.5 KB
  __shared__ __align__(16) _Float16 Vh[CB][VPITCH];   //  4.5 KB
  __shared__ __align__(16) _Float16 Vl[CB][VPITCH];   //  4.5 KB

  const int tid = threadIdx.x;
  const int w = tid >> 6;          // wave 0..3
  const int l = tid & 63;
  const int g = l >> 4;            // k-group 0..3
  const int q = l & 15;            // row/col-in-tile
  const int g0 = blockIdx.x * CB;

  const float Linv = g_sc[0];
  const float wl   = g_sc[1];

  // ---- D fragments into registers (one-time) ----
  // GEMM1 A-frag: lane holds D[w*16+q][ks*32+g*8 + j], j=0..7
  half8 d1h[6], d1l[6];
  if (w < 3) {
    #pragma unroll
    for (int ks = 0; ks < 6; ++ks) {
      const float* src = &g_D[(w*16 + q)*KP + ks*32 + g*8];
      #pragma unroll
      for (int j = 0; j < 8; ++j) {
        const float x = src[j];
        const _Float16 h = (_Float16)x;
        d1h[ks][j] = h;
        d1l[ks][j] = (_Float16)(x - (float)h);
      }
    }
  }
  // GEMM2 A-frag: lane holds DT[(w*3+pi)*16+q][ks*32+g*8 + j]
  half8 d2h[3][2], d2l[3][2];
  #pragma unroll
  for (int pi = 0; pi < 3; ++pi)
    #pragma unroll
    for (int ks = 0; ks < 2; ++ks) {
      const float* src = &g_DT[((w*3 + pi)*16 + q)*KV + ks*32 + g*8];
      #pragma unroll
      for (int j = 0; j < 8; ++j) {
        const float x = src[j];
        const _Float16 h = (_Float16)x;
        d2h[pi][ks][j] = h;
        d2l[pi][ks][j] = (_Float16)(x - (float)h);
      }
    }

  // ---- zero state, stage Y0 tile into V slots (for the cv GEMM) ----
  for (int e = tid; e < CB*YPITCH; e += 256) { (&Yh[0][0])[e] = (_Float16)0; (&Yl[0][0])[e] = (_Float16)0; }
  for (int e = tid; e < CB*VPITCH; e += 256) { (&Vh[0][0])[e] = (_Float16)0; (&Vl[0][0])[e] = (_Float16)0; }
  __syncthreads();
  for (int e = tid; e < CB*T36; e += 256) {
    const int cl = e / T36, t = e % T36;
    const int gc = g0 + cl;
    const int n = gc / 50, m = gc - n*50;
    const float x = y[(size_t)n*1800 + t*50 + m];
    const _Float16 h = (_Float16)x;
    Vh[cl][t] = h;
    Vl[cl][t] = (_Float16)(x - (float)h);
  }
  __syncthreads();

  // ---- cv = Linv * DT x Y0  (GEMM2 path on staged Y0) ----
  float cv[3][2][4], xo[3][2][4], yr[3][2][4];
  {
    f32x4 acc[3][2];
    #pragma unroll
    for (int pi = 0; pi < 3; ++pi)
      #pragma unroll
      for (int ct = 0; ct < 2; ++ct) acc[pi][ct] = (f32x4){0.f,0.f,0.f,0.f};
    #pragma unroll
    for (int ks = 0; ks < 2; ++ks) {
      half8 bh[2], bl[2];
      #pragma unroll
      for (int ct = 0; ct < 2; ++ct) {
        bh[ct] = *reinterpret_cast<const half8*>(&Vh[ct*16 + q][ks*32 + g*8]);
        bl[ct] = *reinterpret_cast<const half8*>(&Vl[ct*16 + q][ks*32 + g*8]);
      }
      #pragma unroll
      for (int pi = 0; pi < 3; ++pi)
        #pragma unroll
        for (int ct = 0; ct < 2; ++ct) {
          acc[pi][ct] = MFMA16(d2h[pi][ks], bh[ct], acc[pi][ct]);
          acc[pi][ct] = MFMA16(d2h[pi][ks], bl[ct], acc[pi][ct]);
          acc[pi][ct] = MFMA16(d2l[pi][ks], bh[ct], acc[pi][ct]);
        }
    }
    #pragma unroll
    for (int pi = 0; pi < 3; ++pi)
      #pragma unroll
      for (int ct = 0; ct < 2; ++ct)
        #pragma unroll
        for (int i = 0; i < 4; ++i) {
          cv[pi][ct][i] = acc[pi][ct][i] * Linv;
          xo[pi][ct][i] = 0.0f;
          yr[pi][ct][i] = 0.0f;
        }
  }

  // ---- FISTA main loop ----
  float tk = 1.0f;
  for (int it = 0; it < 100; ++it) {
    __syncthreads();   // Y-state writes visible (iter 0: zeros)

    // GEMM1: V = D x Y  (waves 0-2; wave's row-tile rt = w)
    if (w < 3) {
      f32x4 a1[2] = {(f32x4){0.f,0.f,0.f,0.f}, (f32x4){0.f,0.f,0.f,0.f}};
      #pragma unroll
      for (int ks = 0; ks < 6; ++ks) {
        half8 bh[2], bl[2];
        #pragma unroll
        for (int ct = 0; ct < 2; ++ct) {
          bh[ct] = *reinterpret_cast<const half8*>(&Yh[ct*16 + q][ks*32 + g*8]);
          bl[ct] = *reinterpret_cast<const half8*>(&Yl[ct*16 + q][ks*32 + g*8]);
        }
        #pragma unroll
        for (int ct = 0; ct < 2; ++ct) {
          a1[ct] = MFMA16(d1h[ks], bh[ct], a1[ct]);
          a1[ct] = MFMA16(d1h[ks], bl[ct], a1[ct]);
          a1[ct] = MFMA16(d1l[ks], bh[ct], a1[ct]);
        }
      }
      // convert + write V: lane owns rows t = w*16 + g*4 + i, col c = ct*16+q
      #pragma unroll
      for (int ct = 0; ct < 2; ++ct) {
        half4 h4, l4;
        #pragma unroll
        for (int i = 0; i < 4; ++i) {
          const float v = a1[ct][i];
          const _Float16 h = (_Float16)v;
          h4[i] = h;
          l4[i] = (_Float16)(v - (float)h);
        }
        *reinterpret_cast<half4*>(&Vh[ct*16 + q][w*16 + g*4]) = h4;
        *reinterpret_cast<half4*>(&Vl[ct*16 + q][w*16 + g*4]) = l4;
      }
    }
    __syncthreads();   // V visible

    // GEMM2: U = DT x V (all waves)
    f32x4 acc[3][2];
    #pragma unroll
    for (int pi = 0; pi < 3; ++pi)
      #pragma unroll
      for (int ct = 0; ct < 2; ++ct) acc[pi][ct] = (f32x4){0.f,0.f,0.f,0.f};
    #pragma unroll
    for (int ks = 0; ks < 2; ++ks) {
      half8 bh[2], bl[2];
      #pragma unroll
      for (int ct = 0; ct < 2; ++ct) {
        bh[ct] = *reinterpret_cast<const half8*>(&Vh[ct*16 + q][ks*32 + g*8]);
        bl[ct] = *reinterpret_cast<const half8*>(&Vl[ct*16 + q][ks*32 + g*8]);
      }
      #pragma unroll
      for (int pi = 0; pi < 3; ++pi)
        #pragma unroll
        for (int ct = 0; ct < 2; ++ct) {
          acc[pi][ct] = MFMA16(d2h[pi][ks], bh[ct], acc[pi][ct]);
          acc[pi][ct] = MFMA16(d2h[pi][ks], bl[ct], acc[pi][ct]);
          acc[pi][ct] = MFMA16(d2l[pi][ks], bh[ct], acc[pi][ct]);
        }
    }

    // momentum scalars
    const float tnew = 0.5f*(1.0f + sqrtf(fmaf(4.0f*tk, tk, 1.0f)));
    const float tt   = (tk - 1.0f) / tnew;
    tk = tnew;

    // elementwise update + write new y-state (lane owns p = (w*3+pi)*16+g*4+i)
    #pragma unroll
    for (int pi = 0; pi < 3; ++pi)
      #pragma unroll
      for (int ct = 0; ct < 2; ++ct) {
        half4 yh4, yl4;
        #pragma unroll
        for (int i = 0; i < 4; ++i) {
          const float u  = acc[pi][ct][i];
          const float gq = fmaf(-Linv, u, yr[pi][ct][i]) + cv[pi][ct][i];
          const float xn = fmaxf(0.0f, gq - wl) + fminf(0.0f, gq + wl);
          const float yn = fmaf(tt, xn - xo[pi][ct][i], xn);
          xo[pi][ct][i] = xn;
          yr[pi][ct][i] = yn;
          const _Float16 h = (_Float16)yn;
          yh4[i] = h;
          yl4[i] = (_Float16)(yn - (float)h);
        }
        const int p0 = (w*3 + pi)*16 + g*4;
        *reinterpret_cast<half4*>(&Yh[ct*16 + q][p0]) = yh4;
        *reinterpret_cast<half4*>(&Yl[ct*16 + q][p0]) = yl4;
      }
  }

  // ---- epilogue ----
  const size_t YP = (size_t)NN * T36 * MM;   // Y_pred floats

  // C_pred = x_final
  #pragma unroll
  for (int pi = 0; pi < 3; ++pi)
    #pragma unroll
    for (int ct = 0; ct < 2; ++ct)
      #pragma unroll
      for (int i = 0; i < 4; ++i) {
        const int p = (w*3 + pi)*16 + g*4 + i;
        if (p < NPAR) {
          const int gc = g0 + ct*16 + q;
          const int n = gc / 50, m = gc - n*50;
          out[YP + (size_t)n*(NPAR*MM) + (size_t)p*MM + m] = xo[pi][ct][i];
        }
      }

  // Y_pred = D x x_final : put x into the Y-state slots, rerun GEMM1
  #pragma unroll
  for (int pi = 0; pi < 3; ++pi)
    #pragma unroll
    for (int ct = 0; ct < 2; ++ct) {
      half4 xh4, xl4;
      #pragma unroll
      for (int i = 0; i < 4; ++i) {
        const float v = xo[pi][ct][i];
        const _Float16 h = (_Float16)v;
        xh4[i] = h;
        xl4[i] = (_Float16)(v - (float)h);
      }
      const int p0 = (w*3 + pi)*16 + g*4;
      *reinterpret_cast<half4*>(&Yh[ct*16 + q][p0]) = xh4;
      *reinterpret_cast<half4*>(&Yl[ct*16 + q][p0]) = xl4;
    }
  __syncthreads();

  if (w < 3) {
    f32x4 a1[2] = {(f32x4){0.f,0.f,0.f,0.f}, (f32x4){0.f,0.f,0.f,0.f}};
    #pragma unroll
    for (int ks = 0; ks < 6; ++ks) {
      half8 bh[2], bl[2];
      #pragma unroll
      for (int ct = 0; ct < 2; ++ct) {
        bh[ct] = *reinterpret_cast<const half8*>(&Yh[ct*16 + q][ks*32 + g*8]);
        bl[ct] = *reinterpret_cast<const half8*>(&Yl[ct*16 + q][ks*32 + g*8]);
      }
      #pragma unroll
      for (int ct = 0; ct < 2; ++ct) {
        a1[ct] = MFMA16(d1h[ks], bh[ct], a1[ct]);
        a1[ct] = MFMA16(d1h[ks], bl[ct], a1[ct]);
        a1[ct] = MFMA16(d1l[ks], bh[ct], a1[ct]);
      }
    }
    #pragma unroll
    for (int ct = 0; ct < 2; ++ct)
      #pragma unroll
      for (int i = 0; i < 4; ++i) {
        const int t = w*16 + g*4 + i;
        if (t < T36) {
          const int gc = g0 + ct*16 + q;
          const int n = gc / 50, m = gc - n*50;
          out[(size_t)n*1800 + t*50 + m] = a1[ct][i];
        }
      }
  }
}

extern "C" void kernel_launch(void* const* d_in, const int* in_sizes, int n_in,
                              void* d_out, int out_size, void* d_ws, size_t ws_size,
                              hipStream_t stream) {
  const float* y  = (const float*)d_in[0];
  const float* r  = (const float*)d_in[1];
  const float* th = (const float*)d_in[2];
  float* out = (float*)d_out;
  (void)d_ws; (void)ws_size;

  setup_kernel<<<1, 256, 0, stream>>>(r, th);
  fista_kernel<<<NCOLS / CB, 256, 0, stream>>>(y, out);
}